// Round 1
// baseline (169.697 us; speedup 1.0000x reference)
//
#include <hip/hip_runtime.h>
#include <math.h>

// floss: weighted BCE with per-batch argmax-centroid weights.
// input/target: [256, 1, 224, 224] fp32. Output: scalar fp32 mean.
//
// One block per batch image (224*224 = 50176 elems). Pass A: streaming
// (max, cnt, sum_i, sum_j) over target; pass B: weighted BCE sum over
// (input, target); one atomicAdd per block into d_out (pre-scaled by 1/N).

#define WIMG 224
#define WW (WIMG * WIMG)      // 50176
#define NQ (WW / 4)           // 12544 float4 per image; 224/4=56 quads/row
#define NB 256
#define NTHREADS 1024
#define LOG_CLAMP -100.0f

__global__ __launch_bounds__(NTHREADS) void floss_kernel(
    const float* __restrict__ input,
    const float* __restrict__ target,
    float* __restrict__ out,
    float inv_total)
{
    const int b   = blockIdx.x;
    const int tid = threadIdx.x;
    const float4* __restrict__ t4 = (const float4*)(target + (size_t)b * WW);
    const float4* __restrict__ p4 = (const float4*)(input  + (size_t)b * WW);

    // ---- Pass A: streaming (max, cnt, sum_i, sum_j) over this image ----
    float m = -1.0f, cnt = 0.0f, si = 0.0f, sj = 0.0f;
    for (int q = tid; q < NQ; q += NTHREADS) {
        float4 v = t4[q];
        int i  = q / 56;            // float4 never crosses a row (224 % 4 == 0)
        int j0 = (q - i * 56) * 4;
        float fi = (float)i;
        float vv[4] = {v.x, v.y, v.z, v.w};
        #pragma unroll
        for (int k = 0; k < 4; ++k) {
            float val = vv[k];
            float fj  = (float)(j0 + k);
            if (val > m)       { m = val; cnt = 1.0f; si = fi; sj = fj; }
            else if (val == m) { cnt += 1.0f; si += fi; sj += fj; }
        }
    }
    // wave(64) argmax-merge reduce
    #pragma unroll
    for (int off = 32; off > 0; off >>= 1) {
        float m2  = __shfl_down(m,   off);
        float c2  = __shfl_down(cnt, off);
        float si2 = __shfl_down(si,  off);
        float sj2 = __shfl_down(sj,  off);
        if (m2 > m)       { m = m2; cnt = c2; si = si2; sj = sj2; }
        else if (m2 == m) { cnt += c2; si += si2; sj += sj2; }
    }
    __shared__ float sm[16], sc[16], ssi[16], ssj[16];
    __shared__ float sxy[2];
    const int lane = tid & 63, wid = tid >> 6;
    if (lane == 0) { sm[wid] = m; sc[wid] = cnt; ssi[wid] = si; ssj[wid] = sj; }
    __syncthreads();
    if (tid == 0) {
        float M = sm[0], C = sc[0], SI = ssi[0], SJ = ssj[0];
        #pragma unroll
        for (int w = 1; w < 16; ++w) {
            float mw = sm[w];
            if (mw > M)       { M = mw; C = sc[w]; SI = ssi[w]; SJ = ssj[w]; }
            else if (mw == M) { C += sc[w]; SI += ssi[w]; SJ += ssj[w]; }
        }
        sxy[0] = SI / C;   // x = mean row index
        sxy[1] = SJ / C;   // y = mean col index
    }
    __syncthreads();
    const float x = sxy[0], y = sxy[1];

    // ---- Pass B: weighted BCE accumulation ----
    float acc = 0.0f;
    for (int q = tid; q < NQ; q += NTHREADS) {
        float4 tv = t4[q];
        float4 pv = p4[q];
        int i  = q / 56;
        int j0 = (q - i * 56) * 4;
        float di  = (float)i - x;
        float di2 = di * di;
        float tt[4] = {tv.x, tv.y, tv.z, tv.w};
        float pp[4] = {pv.x, pv.y, pv.z, pv.w};
        #pragma unroll
        for (int k = 0; k < 4; ++k) {
            float dj   = (float)(j0 + k) - y;
            float dist = (sqrtf(di2 + dj * dj) + 1.0f) / (float)WIMG;
            float wgt  = 1.0f / dist;
            float p = pp[k], t = tt[k];
            float lp  = fmaxf(logf(p),     LOG_CLAMP);
            float l1p = fmaxf(log1pf(-p),  LOG_CLAMP);
            float bce = -(t * lp + (1.0f - t) * l1p);
            acc += wgt * bce;
        }
    }
    // block sum reduce
    #pragma unroll
    for (int off = 32; off > 0; off >>= 1) acc += __shfl_down(acc, off);
    __shared__ float sred[16];
    if (lane == 0) sred[wid] = acc;
    __syncthreads();
    if (tid == 0) {
        float s = 0.0f;
        #pragma unroll
        for (int w = 0; w < 16; ++w) s += sred[w];
        atomicAdd(out, s * inv_total);
    }
}

extern "C" void kernel_launch(void* const* d_in, const int* in_sizes, int n_in,
                              void* d_out, int out_size, void* d_ws, size_t ws_size,
                              hipStream_t stream) {
    const float* input  = (const float*)d_in[0];
    const float* target = (const float*)d_in[1];
    float* out = (float*)d_out;
    // d_out is poisoned 0xAA before every call — zero the accumulator.
    hipMemsetAsync(out, 0, sizeof(float), stream);
    const float inv_total = 1.0f / (256.0f * 224.0f * 224.0f);
    floss_kernel<<<NB, NTHREADS, 0, stream>>>(input, target, out, inv_total);
}

// Round 2
// 124.015 us; speedup vs baseline: 1.3684x; 1.3684x over previous
//
#include <hip/hip_runtime.h>
#include <math.h>

// floss: weighted BCE with per-batch argmax-centroid weights.
// input/target: [256, 1, 224, 224] fp32. Output: scalar fp32 mean.
//
// One block per batch image. Pass A: streaming (max, cnt, sum_i, sum_j) over
// target; pass B: weighted BCE sum using HW fast-math (v_log_f32 / v_rcp_f32 /
// v_sqrt_f32 — libm logf/log1pf + precise divide were 73% VALUBusy in R1);
// one atomicAdd per block into d_out (pre-scaled by 1/N).

#define WIMG 224
#define WW (WIMG * WIMG)      // 50176
#define NQ (WW / 4)           // 12544 float4 per image; 224/4=56 quads/row
#define NB 256
#define NTHREADS 1024
#define LOG_CLAMP -100.0f
#define LN2 0.69314718055994530942f

__device__ __forceinline__ float fast_log(float x) {
    // ln(x) = log2(x) * ln(2); v_log_f32 is ~1 ulp in log2 — far inside the
    // 5.7e-2 absmax threshold on the scalar output.
    return __builtin_amdgcn_logf(x) * LN2;
}

__global__ __launch_bounds__(NTHREADS) void floss_kernel(
    const float* __restrict__ input,
    const float* __restrict__ target,
    float* __restrict__ out,
    float inv_total)
{
    const int b   = blockIdx.x;
    const int tid = threadIdx.x;
    const float4* __restrict__ t4 = (const float4*)(target + (size_t)b * WW);
    const float4* __restrict__ p4 = (const float4*)(input  + (size_t)b * WW);

    // ---- Pass A: streaming (max, cnt, sum_i, sum_j) over this image ----
    float m = -1.0f, cnt = 0.0f, si = 0.0f, sj = 0.0f;
    for (int q = tid; q < NQ; q += NTHREADS) {
        float4 v = t4[q];
        int i  = q / 56;            // float4 never crosses a row (224 % 4 == 0)
        int j0 = (q - i * 56) * 4;
        float fi = (float)i;
        float vv[4] = {v.x, v.y, v.z, v.w};
        #pragma unroll
        for (int k = 0; k < 4; ++k) {
            float val = vv[k];
            float fj  = (float)(j0 + k);
            if (val > m)       { m = val; cnt = 1.0f; si = fi; sj = fj; }
            else if (val == m) { cnt += 1.0f; si += fi; sj += fj; }
        }
    }
    // wave(64) argmax-merge reduce
    #pragma unroll
    for (int off = 32; off > 0; off >>= 1) {
        float m2  = __shfl_down(m,   off);
        float c2  = __shfl_down(cnt, off);
        float si2 = __shfl_down(si,  off);
        float sj2 = __shfl_down(sj,  off);
        if (m2 > m)       { m = m2; cnt = c2; si = si2; sj = sj2; }
        else if (m2 == m) { cnt += c2; si += si2; sj += sj2; }
    }
    __shared__ float sm[16], sc[16], ssi[16], ssj[16];
    __shared__ float sxy[2];
    const int lane = tid & 63, wid = tid >> 6;
    if (lane == 0) { sm[wid] = m; sc[wid] = cnt; ssi[wid] = si; ssj[wid] = sj; }
    __syncthreads();
    if (tid == 0) {
        float M = sm[0], C = sc[0], SI = ssi[0], SJ = ssj[0];
        #pragma unroll
        for (int w = 1; w < 16; ++w) {
            float mw = sm[w];
            if (mw > M)       { M = mw; C = sc[w]; SI = ssi[w]; SJ = ssj[w]; }
            else if (mw == M) { C += sc[w]; SI += ssi[w]; SJ += ssj[w]; }
        }
        sxy[0] = SI / C;   // x = mean row index
        sxy[1] = SJ / C;   // y = mean col index
    }
    __syncthreads();
    const float x = sxy[0], y = sxy[1];

    // ---- Pass B: weighted BCE accumulation (fast-math) ----
    float acc = 0.0f;
    for (int q = tid; q < NQ; q += NTHREADS) {
        float4 tv = t4[q];
        float4 pv = p4[q];
        int i  = q / 56;
        int j0 = (q - i * 56) * 4;
        float di  = (float)i - x;
        float di2 = di * di;
        float tt[4] = {tv.x, tv.y, tv.z, tv.w};
        float pp[4] = {pv.x, pv.y, pv.z, pv.w};
        #pragma unroll
        for (int k = 0; k < 4; ++k) {
            float dj = (float)(j0 + k) - y;
            // weight = WIMG / (sqrt(d2) + 1): v_sqrt + v_rcp, no IEEE divide
            float s   = __builtin_amdgcn_sqrtf(di2 + dj * dj);
            float wgt = (float)WIMG * __builtin_amdgcn_rcpf(s + 1.0f);
            float p = pp[k], t = tt[k];
            float lp  = fmaxf(fast_log(p),        LOG_CLAMP);
            float l1p = fmaxf(fast_log(1.0f - p), LOG_CLAMP);
            float bce = -(t * lp + (1.0f - t) * l1p);
            acc += wgt * bce;
        }
    }
    // block sum reduce
    #pragma unroll
    for (int off = 32; off > 0; off >>= 1) acc += __shfl_down(acc, off);
    __shared__ float sred[16];
    if (lane == 0) sred[wid] = acc;
    __syncthreads();
    if (tid == 0) {
        float s = 0.0f;
        #pragma unroll
        for (int w = 0; w < 16; ++w) s += sred[w];
        atomicAdd(out, s * inv_total);
    }
}

extern "C" void kernel_launch(void* const* d_in, const int* in_sizes, int n_in,
                              void* d_out, int out_size, void* d_ws, size_t ws_size,
                              hipStream_t stream) {
    const float* input  = (const float*)d_in[0];
    const float* target = (const float*)d_in[1];
    float* out = (float*)d_out;
    // d_out is poisoned 0xAA before every call — zero the accumulator.
    hipMemsetAsync(out, 0, sizeof(float), stream);
    const float inv_total = 1.0f / (256.0f * 224.0f * 224.0f);
    floss_kernel<<<NB, NTHREADS, 0, stream>>>(input, target, out, inv_total);
}